// Round 3
// baseline (2418.689 us; speedup 1.0000x reference)
//
#include <hip/hip_runtime.h>

typedef unsigned short u16;
typedef __attribute__((ext_vector_type(8))) short short8;
typedef __attribute__((ext_vector_type(4))) float f32x4;

__device__ __forceinline__ float bf2f(u16 u) {
  unsigned int i = ((unsigned int)u) << 16;
  float f;
  __builtin_memcpy(&f, &i, sizeof(f));
  return f;
}
__device__ __forceinline__ u16 f2bf(float f) {
  unsigned int u;
  __builtin_memcpy(&u, &f, sizeof(u));
  u = (u + 0x7FFFu + ((u >> 16) & 1u)) >> 16;
  return (u16)u;
}

typedef __attribute__((address_space(1))) void* gas_ptr;
typedef __attribute__((address_space(3))) void* las_ptr;

__device__ __forceinline__ void async_load16(const u16* g, u16* lds) {
  __builtin_amdgcn_global_load_lds((gas_ptr)(u16*)g, (las_ptr)lds, 16, 0, 0);
}

// fp32 -> bf16 canonicalization (n divisible by 8).
__global__ __launch_bounds__(256) void convert_in(const float* __restrict__ in,
                                                  u16* __restrict__ out, int n) {
  int i = (blockIdx.x * 256 + threadIdx.x) * 8;
  if (i >= n) return;
  float4 a = *(const float4*)&in[i];
  float4 b = *(const float4*)&in[i + 4];
  union { u16 u[8]; short8 v; } pk;
  pk.u[0] = f2bf(a.x); pk.u[1] = f2bf(a.y); pk.u[2] = f2bf(a.z); pk.u[3] = f2bf(a.w);
  pk.u[4] = f2bf(b.x); pk.u[5] = f2bf(b.y); pk.u[6] = f2bf(b.z); pk.u[7] = f2bf(b.w);
  *(short8*)&out[i] = pk.v;
}

// Stage a 128x32 bf16 tile (row-major, stride ld) into LDS via LDS-DMA.
__device__ __forceinline__ void stage_tile(const u16* gbase, int ld, u16* lds,
                                           int wave, int lane) {
#pragma unroll
  for (int c = 0; c < 2; ++c) {
    const int chunk = wave * 2 + c;  // uniform per wave
    const int row = chunk * 16 + (lane >> 2);
    const int col = (lane & 3) * 8;
    async_load16(gbase + (size_t)row * ld + col, lds + chunk * 512);
  }
}

// C[M,N] = A[M,K] @ W[N,K]^T + bias(fp32) [+relu | +res], bf16 or fp32 out.
// EPI: 0 none, 1 relu, 2 residual. RESF32: res dtype. OUTF32: C dtype.
template <int EPI, int RESF32, int OUTF32>
__global__ __launch_bounds__(256) void gemm_bt(
    const u16* __restrict__ A, const u16* __restrict__ W,
    const float* __restrict__ bias, const void* __restrict__ res,
    void* __restrict__ C, int M, int N, int K) {
  __shared__ u16 As[128 * 32];
  __shared__ u16 Ws[128 * 32];
  const int tid = threadIdx.x;
  const int lane = tid & 63;
  const int wave = tid >> 6;
  const int wm = wave >> 1, wn = wave & 1;
  const size_t row0 = (size_t)blockIdx.y * 128;
  const size_t col0 = (size_t)blockIdx.x * 128;

  f32x4 acc[4][4] = {};

  const u16* Ab = A + row0 * (size_t)K;
  const u16* Wb = W + col0 * (size_t)K;

  for (int k0 = 0; k0 < K; k0 += 32) {
    __syncthreads();
    stage_tile(Ab + k0, K, As, wave, lane);
    stage_tile(Wb + k0, K, Ws, wave, lane);
    __syncthreads();
    short8 af[4], bfr[4];
#pragma unroll
    for (int t = 0; t < 4; ++t) {
      af[t] = *(const short8*)&As[(wm * 64 + t * 16 + (lane & 15)) * 32 + (lane >> 4) * 8];
      bfr[t] = *(const short8*)&Ws[(wn * 64 + t * 16 + (lane & 15)) * 32 + (lane >> 4) * 8];
    }
#pragma unroll
    for (int tm = 0; tm < 4; ++tm)
#pragma unroll
      for (int tn = 0; tn < 4; ++tn)
        acc[tm][tn] = __builtin_amdgcn_mfma_f32_16x16x32_bf16(
            af[tm], bfr[tn], acc[tm][tn], 0, 0, 0);
  }

  // C/D layout (verified m89/m91): col = lane&15, row = (lane>>4)*4 + r
  const int qd = lane >> 4;
  const int l16 = lane & 15;
#pragma unroll
  for (int tn = 0; tn < 4; ++tn) {
    const size_t col = col0 + wn * 64 + tn * 16 + l16;
    const float bv = bias[col];
#pragma unroll
    for (int tm = 0; tm < 4; ++tm) {
#pragma unroll
      for (int r = 0; r < 4; ++r) {
        const size_t row = row0 + wm * 64 + tm * 16 + qd * 4 + r;
        const size_t idx = row * (size_t)N + col;
        float v = acc[tm][tn][r] + bv;
        if (EPI == 1) v = fmaxf(v, 0.f);
        if (EPI == 2) {
          if (RESF32) v += ((const float*)res)[idx];
          else v += bf2f(((const u16*)res)[idx]);
        }
        if (OUTF32) ((float*)C)[idx] = v;
        else ((u16*)C)[idx] = f2bf(v);
      }
    }
  }
}

// Window attention: one block (128 threads) per (window, head).
__global__ __launch_bounds__(128) void attn_win(const u16* __restrict__ qkv,
                                                u16* __restrict__ ctx) {
  __shared__ u16 Ks[128 * 64];
  __shared__ u16 Vs[128 * 64];
  __shared__ u16 Ss[128 * 128];
  const int h = blockIdx.x & 15;
  const int bw = blockIdx.x >> 4;
  const size_t tok0 = (size_t)bw * 128;
  const int r = threadIdx.x;

  const u16* q_g = qkv + (tok0 + r) * 3072 + h * 64;
  const u16* k_g = q_g + 1024;
  const u16* v_g = q_g + 2048;

#pragma unroll
  for (int c0 = 0; c0 < 64; c0 += 8) {
    *(short8*)&Ks[r * 64 + c0] = *(const short8*)&k_g[c0];
    *(short8*)&Vs[r * 64 + c0] = *(const short8*)&v_g[c0];
  }
  float q[64];
#pragma unroll
  for (int c0 = 0; c0 < 64; c0 += 8) {
    short8 t = *(const short8*)&q_g[c0];
#pragma unroll
    for (int j = 0; j < 8; ++j) q[c0 + j] = bf2f((u16)t[j]);
  }
  __syncthreads();

  const float scale = 0.125f;
  float m = -1e30f;
  for (int kk = 0; kk < 128; ++kk) {
    float s = 0.f;
#pragma unroll
    for (int c0 = 0; c0 < 64; c0 += 8) {
      short8 t = *(const short8*)&Ks[kk * 64 + c0];  // wave-broadcast
#pragma unroll
      for (int j = 0; j < 8; ++j) s += q[c0 + j] * bf2f((u16)t[j]);
    }
    s *= scale;
    m = fmaxf(m, s);
    Ss[r * 128 + kk] = f2bf(s);  // own row; same-thread reread, no barrier
  }

  float o[64];
#pragma unroll
  for (int c = 0; c < 64; ++c) o[c] = 0.f;
  float l = 0.f;
  for (int kk = 0; kk < 128; ++kk) {
    float p = __expf(bf2f(Ss[r * 128 + kk]) - m);
    l += p;
#pragma unroll
    for (int c0 = 0; c0 < 64; c0 += 8) {
      short8 t = *(const short8*)&Vs[kk * 64 + c0];  // wave-broadcast
#pragma unroll
      for (int j = 0; j < 8; ++j) o[c0 + j] += p * bf2f((u16)t[j]);
    }
  }
  const float inv = 1.f / l;
  u16* outp = ctx + (tok0 + r) * 1024 + h * 64;
#pragma unroll
  for (int c0 = 0; c0 < 64; c0 += 8) {
    union { u16 u[8]; short8 v; } pk;
#pragma unroll
    for (int j = 0; j < 8; ++j) pk.u[j] = f2bf(o[c0 + j] * inv);
    *(short8*)&outp[c0] = pk.v;
  }
}

// LayerNorm rows of 1024, bf16 in -> bf16 out; gamma/beta fp32. In-place safe.
__global__ __launch_bounds__(256) void ln_bf16(
    const u16* __restrict__ x, const float* __restrict__ g,
    const float* __restrict__ b, u16* __restrict__ y) {
  const int lane = threadIdx.x & 63;
  const int wave = threadIdx.x >> 6;
  const size_t row = (size_t)blockIdx.x * 4 + wave;
  const u16* xr = x + row * 1024 + lane * 16;
  float v[16];
#pragma unroll
  for (int c0 = 0; c0 < 16; c0 += 8) {
    short8 t = *(const short8*)&xr[c0];
#pragma unroll
    for (int j = 0; j < 8; ++j) v[c0 + j] = bf2f((u16)t[j]);
  }
  float s = 0.f;
#pragma unroll
  for (int c = 0; c < 16; ++c) s += v[c];
#pragma unroll
  for (int off = 32; off; off >>= 1) s += __shfl_xor(s, off, 64);
  const float mu = s * (1.f / 1024.f);
  float var = 0.f;
#pragma unroll
  for (int c = 0; c < 16; ++c) {
    float d = v[c] - mu;
    var += d * d;
  }
#pragma unroll
  for (int off = 32; off; off >>= 1) var += __shfl_xor(var, off, 64);
  const float rs = rsqrtf(var * (1.f / 1024.f) + 1e-5f);
  u16* yp = y + row * 1024 + lane * 16;
#pragma unroll
  for (int c0 = 0; c0 < 16; c0 += 8) {
    float4 tg = *(const float4*)&g[lane * 16 + c0];
    float4 tb = *(const float4*)&b[lane * 16 + c0];
    float4 tg2 = *(const float4*)&g[lane * 16 + c0 + 4];
    float4 tb2 = *(const float4*)&b[lane * 16 + c0 + 4];
    const float gg[8] = {tg.x, tg.y, tg.z, tg.w, tg2.x, tg2.y, tg2.z, tg2.w};
    const float bb[8] = {tb.x, tb.y, tb.z, tb.w, tb2.x, tb2.y, tb2.z, tb2.w};
    union { u16 u[8]; short8 vv; } pk;
#pragma unroll
    for (int j = 0; j < 8; ++j)
      pk.u[j] = f2bf((v[c0 + j] - mu) * rs * gg[j] + bb[j]);
    *(short8*)&yp[c0] = pk.vv;
  }
}

// LayerNorm rows of 1024, fp32 in -> fp32 out. In-place safe.
__global__ __launch_bounds__(256) void ln_f32(
    const float* __restrict__ x, const float* __restrict__ g,
    const float* __restrict__ b, float* __restrict__ y) {
  const int lane = threadIdx.x & 63;
  const int wave = threadIdx.x >> 6;
  const size_t row = (size_t)blockIdx.x * 4 + wave;
  const float* xr = x + row * 1024 + lane * 16;
  float v[16];
#pragma unroll
  for (int c0 = 0; c0 < 16; c0 += 4) {
    float4 t = *(const float4*)&xr[c0];
    v[c0] = t.x; v[c0 + 1] = t.y; v[c0 + 2] = t.z; v[c0 + 3] = t.w;
  }
  float s = 0.f;
#pragma unroll
  for (int c = 0; c < 16; ++c) s += v[c];
#pragma unroll
  for (int off = 32; off; off >>= 1) s += __shfl_xor(s, off, 64);
  const float mu = s * (1.f / 1024.f);
  float var = 0.f;
#pragma unroll
  for (int c = 0; c < 16; ++c) {
    float d = v[c] - mu;
    var += d * d;
  }
#pragma unroll
  for (int off = 32; off; off >>= 1) var += __shfl_xor(var, off, 64);
  const float rs = rsqrtf(var * (1.f / 1024.f) + 1e-5f);
  float* yp = y + row * 1024 + lane * 16;
#pragma unroll
  for (int c0 = 0; c0 < 16; c0 += 4) {
    float4 tg = *(const float4*)&g[lane * 16 + c0];
    float4 tb = *(const float4*)&b[lane * 16 + c0];
    float4 o;
    o.x = (v[c0] - mu) * rs * tg.x + tb.x;
    o.y = (v[c0 + 1] - mu) * rs * tg.y + tb.y;
    o.z = (v[c0 + 2] - mu) * rs * tg.z + tb.z;
    o.w = (v[c0 + 3] - mu) * rs * tg.w + tb.w;
    *(float4*)&yp[c0] = o;
  }
}

extern "C" void kernel_launch(void* const* d_in, const int* in_sizes, int n_in,
                              void* d_out, int out_size, void* d_ws,
                              size_t ws_size, hipStream_t stream) {
  const float* src_f = (const float*)d_in[0];
  const float* in_proj_b = (const float*)d_in[2];
  const float* out_proj_b = (const float*)d_in[4];
  const float* b1 = (const float*)d_in[6];
  const float* b2 = (const float*)d_in[8];
  const float* ln1_g = (const float*)d_in[9];
  const float* ln1_b = (const float*)d_in[10];
  const float* ln2_g = (const float*)d_in[11];
  const float* ln2_b = (const float*)d_in[12];
  float* out = (float*)d_out;  // reference output dtype: fp32

  char* ws = (char*)d_ws;
  const size_t MB = 1024 * 1024;
  // ws layout (peak 352 MiB; rounds 1-2 proved >=384 MiB accessible):
  u16* csrc  = (u16*)(ws);                // [0, 64M)
  u16* cwin  = (u16*)(ws + 64 * MB);      // [64M, 70M)
  u16* cwout = (u16*)(ws + 70 * MB);      // [70M, 72M)
  u16* cw1   = (u16*)(ws + 72 * MB);      // [72M, 80M)
  u16* cw2   = (u16*)(ws + 80 * MB);      // [80M, 88M)
  u16* qkv   = (u16*)(ws + 96 * MB);      // [96M, 288M)
  u16* ctxb  = (u16*)(ws + 288 * MB);     // [288M, 352M)
  u16* hbuf  = (u16*)(ws + 96 * MB);      // [96M, 160M)  (qkv dead by then)
  u16* ffbuf = (u16*)(ws + 160 * MB);     // [160M, 288M) (one 16384-row half)

  // Canonicalize the 5 matrices to bf16 (biases/gains stay fp32).
  const int cvt_idx[5] = {0, 1, 3, 5, 7};
  u16* cvt_dst[5] = {csrc, cwin, cwout, cw1, cw2};
  for (int i = 0; i < 5; ++i) {
    int n = in_sizes[cvt_idx[i]];
    convert_in<<<(n / 8 + 255) / 256, 256, 0, stream>>>(
        (const float*)d_in[cvt_idx[i]], cvt_dst[i], n);
  }

  const int M = 32768;  // 4 * 8192 tokens
  dim3 blk(256);
  // 1) qkv = src @ in_proj_w^T + in_proj_b
  gemm_bt<0, 0, 0><<<dim3(24, 256), blk, 0, stream>>>(csrc, cwin, in_proj_b,
                                                      nullptr, qkv, M, 3072, 1024);
  // 2) window attention -> ctx
  attn_win<<<dim3(4096), dim3(128), 0, stream>>>(qkv, ctxb);
  // 3) preln1 = ctx @ out_proj_w^T + out_proj_b + src(fp32)  -> hbuf (bf16)
  gemm_bt<2, 1, 0><<<dim3(8, 256), blk, 0, stream>>>(ctxb, cwout, out_proj_b,
                                                     src_f, hbuf, M, 1024, 1024);
  // 4) h = LN(preln1), in place (bf16)
  ln_bf16<<<dim3(8192), blk, 0, stream>>>(hbuf, ln1_g, ln1_b, hbuf);
  // 5/6) FF in two 16384-row halves; preln2 written to d_out as fp32
  for (int half = 0; half < 2; ++half) {
    const u16* hA = hbuf + (size_t)half * 16384 * 1024;
    float* oC = out + (size_t)half * 16384 * 1024;
    gemm_bt<1, 0, 0><<<dim3(32, 128), blk, 0, stream>>>(hA, cw1, b1, nullptr,
                                                        ffbuf, 16384, 4096, 1024);
    gemm_bt<2, 0, 1><<<dim3(8, 128), blk, 0, stream>>>(ffbuf, cw2, b2, hA, oC,
                                                       16384, 1024, 4096);
  }
  // 7) out = LN(out), fp32 in place
  ln_f32<<<dim3(8192), blk, 0, stream>>>(out, ln2_g, ln2_b, out);
}

// Round 4
// 1857.601 us; speedup vs baseline: 1.3020x; 1.3020x over previous
//
#include <hip/hip_runtime.h>

typedef unsigned short u16;
typedef __attribute__((ext_vector_type(8))) short short8;
typedef __attribute__((ext_vector_type(4))) float f32x4;

__device__ __forceinline__ float bf2f(u16 u) {
  unsigned int i = ((unsigned int)u) << 16;
  float f;
  __builtin_memcpy(&f, &i, sizeof(f));
  return f;
}
__device__ __forceinline__ u16 f2bf(float f) {
  unsigned int u;
  __builtin_memcpy(&u, &f, sizeof(u));
  u = (u + 0x7FFFu + ((u >> 16) & 1u)) >> 16;
  return (u16)u;
}

typedef __attribute__((address_space(1))) void* gas_ptr;
typedef __attribute__((address_space(3))) void* las_ptr;

__device__ __forceinline__ void async_load16(const u16* g, u16* lds) {
  __builtin_amdgcn_global_load_lds((gas_ptr)(u16*)g, (las_ptr)lds, 16, 0, 0);
}

// fp32 -> bf16 canonicalization (n divisible by 8).
__global__ __launch_bounds__(256) void convert_in(const float* __restrict__ in,
                                                  u16* __restrict__ out, int n) {
  int i = (blockIdx.x * 256 + threadIdx.x) * 8;
  if (i >= n) return;
  float4 a = *(const float4*)&in[i];
  float4 b = *(const float4*)&in[i + 4];
  union { u16 u[8]; short8 v; } pk;
  pk.u[0] = f2bf(a.x); pk.u[1] = f2bf(a.y); pk.u[2] = f2bf(a.z); pk.u[3] = f2bf(a.w);
  pk.u[4] = f2bf(b.x); pk.u[5] = f2bf(b.y); pk.u[6] = f2bf(b.z); pk.u[7] = f2bf(b.w);
  *(short8*)&out[i] = pk.v;
}

// Stage a 128x32 bf16 tile (row-major, stride ld) into LDS via LDS-DMA.
__device__ __forceinline__ void stage_tile(const u16* gbase, int ld, u16* lds,
                                           int wave, int lane) {
#pragma unroll
  for (int c = 0; c < 2; ++c) {
    const int chunk = wave * 2 + c;  // uniform per wave
    const int row = chunk * 16 + (lane >> 2);
    const int col = (lane & 3) * 8;
    async_load16(gbase + (size_t)row * ld + col, lds + chunk * 512);
  }
}

// C[M,N] = A[M,K] @ W[N,K]^T + bias(fp32) [+relu | +res], bf16 or fp32 out.
template <int EPI, int RESF32, int OUTF32>
__global__ __launch_bounds__(256) void gemm_bt(
    const u16* __restrict__ A, const u16* __restrict__ W,
    const float* __restrict__ bias, const void* __restrict__ res,
    void* __restrict__ C, int M, int N, int K) {
  __shared__ u16 As[128 * 32];
  __shared__ u16 Ws[128 * 32];
  const int tid = threadIdx.x;
  const int lane = tid & 63;
  const int wave = tid >> 6;
  const int wm = wave >> 1, wn = wave & 1;
  const size_t row0 = (size_t)blockIdx.y * 128;
  const size_t col0 = (size_t)blockIdx.x * 128;

  f32x4 acc[4][4] = {};

  const u16* Ab = A + row0 * (size_t)K;
  const u16* Wb = W + col0 * (size_t)K;

  for (int k0 = 0; k0 < K; k0 += 32) {
    __syncthreads();
    stage_tile(Ab + k0, K, As, wave, lane);
    stage_tile(Wb + k0, K, Ws, wave, lane);
    __syncthreads();
    short8 af[4], bfr[4];
#pragma unroll
    for (int t = 0; t < 4; ++t) {
      af[t] = *(const short8*)&As[(wm * 64 + t * 16 + (lane & 15)) * 32 + (lane >> 4) * 8];
      bfr[t] = *(const short8*)&Ws[(wn * 64 + t * 16 + (lane & 15)) * 32 + (lane >> 4) * 8];
    }
#pragma unroll
    for (int tm = 0; tm < 4; ++tm)
#pragma unroll
      for (int tn = 0; tn < 4; ++tn)
        acc[tm][tn] = __builtin_amdgcn_mfma_f32_16x16x32_bf16(
            af[tm], bfr[tn], acc[tm][tn], 0, 0, 0);
  }

  // C/D layout (verified m89/m91): col = lane&15, row = (lane>>4)*4 + r
  const int qd = lane >> 4;
  const int l16 = lane & 15;
#pragma unroll
  for (int tn = 0; tn < 4; ++tn) {
    const size_t col = col0 + wn * 64 + tn * 16 + l16;
    const float bv = bias[col];
#pragma unroll
    for (int tm = 0; tm < 4; ++tm) {
#pragma unroll
      for (int r = 0; r < 4; ++r) {
        const size_t row = row0 + wm * 64 + tm * 16 + qd * 4 + r;
        const size_t idx = row * (size_t)N + col;
        float v = acc[tm][tn][r] + bv;
        if (EPI == 1) v = fmaxf(v, 0.f);
        if (EPI == 2) {
          if (RESF32) v += ((const float*)res)[idx];
          else v += bf2f(((const u16*)res)[idx]);
        }
        if (OUTF32) ((float*)C)[idx] = v;
        else ((u16*)C)[idx] = f2bf(v);
      }
    }
  }
}

// ---- MFMA window attention ----
// One block (256 threads = 4 waves) per (window, head). Wave w owns S/O rows
// [32w, 32w+32). Q,K A/B-frags loaded directly from global (16B chunks tile
// 64B lines). V transposed into LDS once; P round-trips through LDS to move
// from MFMA C-layout to A-operand layout (m120 pattern).
#define VS 132  // Vt row stride in u16 (pad 4: frag reads <=2-way -> free)
#define PS 132  // Ps row stride in u16

__global__ __launch_bounds__(256) void attn_mfma(const u16* __restrict__ qkv,
                                                 u16* __restrict__ ctx) {
  __shared__ u16 Vt[64 * VS];   // Vt[n][k] = V[k][n]   (16.9 KiB)
  __shared__ u16 Ps[128 * PS];  // P bf16 row-major     (33.8 KiB)
  const int h = blockIdx.x & 15;
  const int bw = blockIdx.x >> 4;
  const size_t tok0 = (size_t)bw * 128;
  const int tid = threadIdx.x;
  const int lane = tid & 63;
  const int wave = tid >> 6;
  const int l16 = lane & 15;
  const int quad = lane >> 4;
  const int row_base = wave * 32;

  const u16* base = qkv + tok0 * 3072 + h * 64;  // +1024 = K, +2048 = V

  // ---- stage V^T into LDS (each thread: one 32-col half of one V row) ----
  {
    const int k = tid >> 1;
    const int c0 = (tid & 1) * 32;
    const u16* vrow = base + (size_t)k * 3072 + 2048 + c0;
    short8 va = *(const short8*)&vrow[0];
    short8 vb = *(const short8*)&vrow[8];
    short8 vc = *(const short8*)&vrow[16];
    short8 vd = *(const short8*)&vrow[24];
#pragma unroll
    for (int j = 0; j < 8; ++j) {
      Vt[(c0 + j) * VS + k] = (u16)va[j];
      Vt[(c0 + 8 + j) * VS + k] = (u16)vb[j];
      Vt[(c0 + 16 + j) * VS + k] = (u16)vc[j];
      Vt[(c0 + 24 + j) * VS + k] = (u16)vd[j];
    }
  }

  // ---- S = Q K^T (raw; scale folded into softmax) ----
  f32x4 sacc[2][8] = {};
#pragma unroll
  for (int ks = 0; ks < 2; ++ks) {
    short8 qf[2], kf[8];
#pragma unroll
    for (int tm = 0; tm < 2; ++tm)
      qf[tm] = *(const short8*)(base +
          (size_t)(row_base + tm * 16 + l16) * 3072 + ks * 32 + quad * 8);
#pragma unroll
    for (int tn = 0; tn < 8; ++tn)
      kf[tn] = *(const short8*)(base +
          (size_t)(tn * 16 + l16) * 3072 + 1024 + ks * 32 + quad * 8);
#pragma unroll
    for (int tm = 0; tm < 2; ++tm)
#pragma unroll
      for (int tn = 0; tn < 8; ++tn)
        sacc[tm][tn] = __builtin_amdgcn_mfma_f32_16x16x32_bf16(
            qf[tm], kf[tn], sacc[tm][tn], 0, 0, 0);
  }

  // ---- softmax over rows (row = row_base + tm*16 + quad*4 + r) ----
  const float scale = 0.125f;  // 1/sqrt(64)
  float inv_l[2][4];
#pragma unroll
  for (int tm = 0; tm < 2; ++tm) {
#pragma unroll
    for (int r = 0; r < 4; ++r) {
      float mx = -1e30f;
#pragma unroll
      for (int tn = 0; tn < 8; ++tn) mx = fmaxf(mx, sacc[tm][tn][r]);
      mx = fmaxf(mx, __shfl_xor(mx, 1, 64));
      mx = fmaxf(mx, __shfl_xor(mx, 2, 64));
      mx = fmaxf(mx, __shfl_xor(mx, 4, 64));
      mx = fmaxf(mx, __shfl_xor(mx, 8, 64));
      float lsum = 0.f;
#pragma unroll
      for (int tn = 0; tn < 8; ++tn) {
        float p = __expf((sacc[tm][tn][r] - mx) * scale);
        lsum += p;
        sacc[tm][tn][r] = p;
      }
      lsum += __shfl_xor(lsum, 1, 64);
      lsum += __shfl_xor(lsum, 2, 64);
      lsum += __shfl_xor(lsum, 4, 64);
      lsum += __shfl_xor(lsum, 8, 64);
      inv_l[tm][r] = 1.f / lsum;
    }
  }

  // ---- write P (bf16) to LDS in row-major for A-frag reads ----
#pragma unroll
  for (int tm = 0; tm < 2; ++tm)
#pragma unroll
    for (int tn = 0; tn < 8; ++tn)
#pragma unroll
      for (int r = 0; r < 4; ++r)
        Ps[(row_base + tm * 16 + quad * 4 + r) * PS + tn * 16 + l16] =
            f2bf(sacc[tm][tn][r]);

  __syncthreads();  // Vt + Ps visible to all waves

  // ---- O = P V ----
  f32x4 oacc[2][4] = {};
#pragma unroll
  for (int ks = 0; ks < 4; ++ks) {
    short8 pf[2], vf[4];
#pragma unroll
    for (int tm = 0; tm < 2; ++tm)
      pf[tm] = *(const short8*)&Ps[(row_base + tm * 16 + l16) * PS +
                                   ks * 32 + quad * 8];
#pragma unroll
    for (int tn = 0; tn < 4; ++tn)
      vf[tn] = *(const short8*)&Vt[(tn * 16 + l16) * VS + ks * 32 + quad * 8];
#pragma unroll
    for (int tm = 0; tm < 2; ++tm)
#pragma unroll
      for (int tn = 0; tn < 4; ++tn)
        oacc[tm][tn] = __builtin_amdgcn_mfma_f32_16x16x32_bf16(
            pf[tm], vf[tn], oacc[tm][tn], 0, 0, 0);
  }

  // ---- epilogue: normalize and store (inv_l already in the right lanes) ----
  u16* cb = ctx + tok0 * 1024 + h * 64;
#pragma unroll
  for (int tm = 0; tm < 2; ++tm)
#pragma unroll
    for (int tn = 0; tn < 4; ++tn)
#pragma unroll
      for (int r = 0; r < 4; ++r)
        cb[(size_t)(row_base + tm * 16 + quad * 4 + r) * 1024 + tn * 16 + l16] =
            f2bf(oacc[tm][tn][r] * inv_l[tm][r]);
}

// LayerNorm rows of 1024, bf16 in -> bf16 out; gamma/beta fp32. In-place safe.
__global__ __launch_bounds__(256) void ln_bf16(
    const u16* __restrict__ x, const float* __restrict__ g,
    const float* __restrict__ b, u16* __restrict__ y) {
  const int lane = threadIdx.x & 63;
  const int wave = threadIdx.x >> 6;
  const size_t row = (size_t)blockIdx.x * 4 + wave;
  const u16* xr = x + row * 1024 + lane * 16;
  float v[16];
#pragma unroll
  for (int c0 = 0; c0 < 16; c0 += 8) {
    short8 t = *(const short8*)&xr[c0];
#pragma unroll
    for (int j = 0; j < 8; ++j) v[c0 + j] = bf2f((u16)t[j]);
  }
  float s = 0.f;
#pragma unroll
  for (int c = 0; c < 16; ++c) s += v[c];
#pragma unroll
  for (int off = 32; off; off >>= 1) s += __shfl_xor(s, off, 64);
  const float mu = s * (1.f / 1024.f);
  float var = 0.f;
#pragma unroll
  for (int c = 0; c < 16; ++c) {
    float d = v[c] - mu;
    var += d * d;
  }
#pragma unroll
  for (int off = 32; off; off >>= 1) var += __shfl_xor(var, off, 64);
  const float rs = rsqrtf(var * (1.f / 1024.f) + 1e-5f);
  u16* yp = y + row * 1024 + lane * 16;
#pragma unroll
  for (int c0 = 0; c0 < 16; c0 += 8) {
    float4 tg = *(const float4*)&g[lane * 16 + c0];
    float4 tb = *(const float4*)&b[lane * 16 + c0];
    float4 tg2 = *(const float4*)&g[lane * 16 + c0 + 4];
    float4 tb2 = *(const float4*)&b[lane * 16 + c0 + 4];
    const float gg[8] = {tg.x, tg.y, tg.z, tg.w, tg2.x, tg2.y, tg2.z, tg2.w};
    const float bb[8] = {tb.x, tb.y, tb.z, tb.w, tb2.x, tb2.y, tb2.z, tb2.w};
    union { u16 u[8]; short8 vv; } pk;
#pragma unroll
    for (int j = 0; j < 8; ++j)
      pk.u[j] = f2bf((v[c0 + j] - mu) * rs * gg[j] + bb[j]);
    *(short8*)&yp[c0] = pk.vv;
  }
}

// LayerNorm rows of 1024, fp32 in -> fp32 out. In-place safe.
__global__ __launch_bounds__(256) void ln_f32(
    const float* __restrict__ x, const float* __restrict__ g,
    const float* __restrict__ b, float* __restrict__ y) {
  const int lane = threadIdx.x & 63;
  const int wave = threadIdx.x >> 6;
  const size_t row = (size_t)blockIdx.x * 4 + wave;
  const float* xr = x + row * 1024 + lane * 16;
  float v[16];
#pragma unroll
  for (int c0 = 0; c0 < 16; c0 += 4) {
    float4 t = *(const float4*)&xr[c0];
    v[c0] = t.x; v[c0 + 1] = t.y; v[c0 + 2] = t.z; v[c0 + 3] = t.w;
  }
  float s = 0.f;
#pragma unroll
  for (int c = 0; c < 16; ++c) s += v[c];
#pragma unroll
  for (int off = 32; off; off >>= 1) s += __shfl_xor(s, off, 64);
  const float mu = s * (1.f / 1024.f);
  float var = 0.f;
#pragma unroll
  for (int c = 0; c < 16; ++c) {
    float d = v[c] - mu;
    var += d * d;
  }
#pragma unroll
  for (int off = 32; off; off >>= 1) var += __shfl_xor(var, off, 64);
  const float rs = rsqrtf(var * (1.f / 1024.f) + 1e-5f);
  float* yp = y + row * 1024 + lane * 16;
#pragma unroll
  for (int c0 = 0; c0 < 16; c0 += 4) {
    float4 tg = *(const float4*)&g[lane * 16 + c0];
    float4 tb = *(const float4*)&b[lane * 16 + c0];
    float4 o;
    o.x = (v[c0] - mu) * rs * tg.x + tb.x;
    o.y = (v[c0 + 1] - mu) * rs * tg.y + tb.y;
    o.z = (v[c0 + 2] - mu) * rs * tg.z + tb.z;
    o.w = (v[c0 + 3] - mu) * rs * tg.w + tb.w;
    *(float4*)&yp[c0] = o;
  }
}

extern "C" void kernel_launch(void* const* d_in, const int* in_sizes, int n_in,
                              void* d_out, int out_size, void* d_ws,
                              size_t ws_size, hipStream_t stream) {
  const float* src_f = (const float*)d_in[0];
  const float* in_proj_b = (const float*)d_in[2];
  const float* out_proj_b = (const float*)d_in[4];
  const float* b1 = (const float*)d_in[6];
  const float* b2 = (const float*)d_in[8];
  const float* ln1_g = (const float*)d_in[9];
  const float* ln1_b = (const float*)d_in[10];
  const float* ln2_g = (const float*)d_in[11];
  const float* ln2_b = (const float*)d_in[12];
  float* out = (float*)d_out;  // reference output dtype: fp32

  char* ws = (char*)d_ws;
  const size_t MB = 1024 * 1024;
  u16* csrc  = (u16*)(ws);                // [0, 64M)
  u16* cwin  = (u16*)(ws + 64 * MB);      // [64M, 70M)
  u16* cwout = (u16*)(ws + 70 * MB);      // [70M, 72M)
  u16* cw1   = (u16*)(ws + 72 * MB);      // [72M, 80M)
  u16* cw2   = (u16*)(ws + 80 * MB);      // [80M, 88M)
  u16* qkv   = (u16*)(ws + 96 * MB);      // [96M, 288M)
  u16* ctxb  = (u16*)(ws + 288 * MB);     // [288M, 352M)
  u16* hbuf  = (u16*)(ws + 96 * MB);      // [96M, 160M)  (qkv dead by then)
  u16* ffbuf = (u16*)(ws + 160 * MB);     // [160M, 288M) (one 16384-row half)

  const int cvt_idx[5] = {0, 1, 3, 5, 7};
  u16* cvt_dst[5] = {csrc, cwin, cwout, cw1, cw2};
  for (int i = 0; i < 5; ++i) {
    int n = in_sizes[cvt_idx[i]];
    convert_in<<<(n / 8 + 255) / 256, 256, 0, stream>>>(
        (const float*)d_in[cvt_idx[i]], cvt_dst[i], n);
  }

  const int M = 32768;  // 4 * 8192 tokens
  dim3 blk(256);
  // 1) qkv = src @ in_proj_w^T + in_proj_b
  gemm_bt<0, 0, 0><<<dim3(24, 256), blk, 0, stream>>>(csrc, cwin, in_proj_b,
                                                      nullptr, qkv, M, 3072, 1024);
  // 2) window attention -> ctx (MFMA)
  attn_mfma<<<dim3(4096), dim3(256), 0, stream>>>(qkv, ctxb);
  // 3) preln1 = ctx @ out_proj_w^T + out_proj_b + src(fp32)  -> hbuf (bf16)
  gemm_bt<2, 1, 0><<<dim3(8, 256), blk, 0, stream>>>(ctxb, cwout, out_proj_b,
                                                     src_f, hbuf, M, 1024, 1024);
  // 4) h = LN(preln1), in place (bf16)
  ln_bf16<<<dim3(8192), blk, 0, stream>>>(hbuf, ln1_g, ln1_b, hbuf);
  // 5/6) FF in two 16384-row halves; preln2 written to d_out as fp32
  for (int half = 0; half < 2; ++half) {
    const u16* hA = hbuf + (size_t)half * 16384 * 1024;
    float* oC = out + (size_t)half * 16384 * 1024;
    gemm_bt<1, 0, 0><<<dim3(32, 128), blk, 0, stream>>>(hA, cw1, b1, nullptr,
                                                        ffbuf, 16384, 4096, 1024);
    gemm_bt<2, 0, 1><<<dim3(8, 128), blk, 0, stream>>>(ffbuf, cw2, b2, hA, oC,
                                                       16384, 1024, 4096);
  }
  // 7) out = LN(out), fp32 in place
  ln_f32<<<dim3(8192), blk, 0, stream>>>(out, ln2_g, ln2_b, out);
}